// Round 16
// baseline (149.899 us; speedup 1.0000x reference)
//
#include <hip/hip_runtime.h>

typedef _Float16 f16;
typedef _Float16 f16x4 __attribute__((ext_vector_type(4)));
typedef _Float16 f16x8 __attribute__((ext_vector_type(8)));
typedef float f32x4 __attribute__((ext_vector_type(4)));

#define B_TOT 16384
#define LAT_  16
#define STY_  64
#define ND_   8

#define ROWS 32            // rows per block, held in LDS through all 8 layers
#define NTHR 512           // 8 waves
#define NBLK 512           // B_TOT / ROWS -> 2 blocks/CU (cross-block overlap)

// act LDS layout: f16 [16 kt][2 m][4 lg][16 lr][8]  (32 KB, no pad).
// af fragment read (fixed kt,m): lane (lr+16*lg) reads byte
//   (kt*2+m)*1024 + lg*256 + lr*16 == base + lane*16 -> contiguous 1KB/wave,
// zero bank conflicts. Element (row r, col k):
//   byte = ((k>>5)*2 + (r>>4))*1024 + ((k>>3)&3)*256 + (r&15)*16 + (k&7)*2

// ---------------- prep: transpose+cast all weights into k-tiled fragment layout -
// dst elem (out-col n, k) -> dst[((k>>5)*NR + n)*32 + (k&31)]   (f16)
__global__ void prep_k(const float* W0, f16* Wt0, const float* W1, f16* Wt1,
                       const float* W2, f16* Wt2, const float* W3, f16* Wt3,
                       const float* U0, f16* U0t, const float* U1, f16* U1t,
                       const float* U2, f16* U2t, const float* U3, f16* U3t) {
  int z = blockIdx.z;
  const float* src; f16* dst; int Kin, Nin, Kpad, NR;
  if (z == 0)      { src = W0; dst = Wt0; Kin = 16;  Nin = 512; Kpad = 32;  NR = 512; }
  else if (z == 1) { src = W1; dst = Wt1; Kin = 512; Nin = 512; Kpad = 512; NR = 512; }
  else if (z == 2) { src = W2; dst = Wt2; Kin = 512; Nin = 512; Kpad = 512; NR = 512; }
  else if (z == 3) { src = W3; dst = Wt3; Kin = 512; Nin = 512; Kpad = 512; NR = 512; }
  else if (z < 12) { int d = z - 4;  src = U0 + (long)d * 262144; dst = U0t + (long)d * 262144; Kin = 512; Nin = 512; Kpad = 512; NR = 512; }
  else if (z < 20) { int d = z - 12; src = U1 + (long)d * 262144; dst = U1t + (long)d * 262144; Kin = 512; Nin = 512; Kpad = 512; NR = 512; }
  else if (z < 28) { int d = z - 20; src = U2 + (long)d * 262144; dst = U2t + (long)d * 262144; Kin = 512; Nin = 512; Kpad = 512; NR = 512; }
  else             { int d = z - 28; src = U3 + (long)d * 32768;  dst = U3t + (long)d * 32768;  Kin = 512; Nin = 64;  Kpad = 512; NR = 64; }

  __shared__ float tile[32][33];
  int k0 = blockIdx.y * 32, n0 = blockIdx.x * 32;
  int tx = threadIdx.x, ty = threadIdx.y;  // 32 x 8
  #pragma unroll
  for (int i = 0; i < 32; i += 8) {
    int k = k0 + ty + i, n = n0 + tx;
    tile[ty + i][tx] = (k < Kin && n < Nin) ? src[(long)k * Nin + n] : 0.f;
  }
  __syncthreads();
  #pragma unroll
  for (int i = 0; i < 32; i += 8) {
    int n = n0 + ty + i, k = k0 + tx;
    if (n < NR && k < Kpad)
      dst[(long)(((k >> 5) * NR + n) << 5) | (k & 31)] = (f16)tile[tx][ty + i];
  }
}

// ---------------- bucketing (atomics-free, deterministic) ----------------
#define NT_BUCKET 1024
#define RPT 16

__global__ __launch_bounds__(NT_BUCKET) void bucket_k(const int* __restrict__ y,
                                                      int* __restrict__ offsets,
                                                      int* __restrict__ perm) {
  __shared__ int hist[ND_][NT_BUCKET];
  __shared__ int totals[ND_];
  __shared__ int bases[ND_ + 1];
  int t = threadIdx.x;
  int base = t * RPT;

  #pragma unroll
  for (int d = 0; d < ND_; d++) hist[d][t] = 0;
  int yv[RPT];
  #pragma unroll
  for (int i = 0; i < RPT; i++) {
    yv[i] = y[base + i];
    hist[yv[i]][t]++;
  }
  __syncthreads();

  int wave = t >> 6, lane = t & 63;
  if (wave < ND_) {
    int d = wave;
    int carry = 0;
    for (int c = 0; c < NT_BUCKET; c += 64) {
      int v = hist[d][c + lane];
      int s = v;
      #pragma unroll
      for (int off = 1; off < 64; off <<= 1) {
        int u = __shfl_up(s, off, 64);
        if (lane >= off) s += u;
      }
      hist[d][c + lane] = carry + s - v;   // exclusive prefix
      carry += __shfl(s, 63, 64);
    }
    if (lane == 0) totals[d] = carry;
  }
  __syncthreads();

  if (t == 0) {
    int s = 0;
    #pragma unroll
    for (int d = 0; d < ND_; d++) { bases[d] = s; offsets[d] = s; s += totals[d]; }
    offsets[ND_] = s;
  }
  __syncthreads();

  #pragma unroll
  for (int i = 0; i < RPT; i++) {
    int d = yv[i];
    int pos = bases[d] + hist[d][t];
    hist[d][t]++;
    perm[pos] = base + i;
  }
}

#define MFMA_(b, a, c) __builtin_amdgcn_mfma_f32_16x16x32_f16((b), (a), (c), 0, 0, 0)

// ---------------- fused layer ----------------
// 8 waves; wave wid owns out-cols [wid*64, wid*64+64) (NF=4), rows via MF=2.
// Weights k-tiled [KT][NR][32]; bf global->VGPR, 4-buffer, distance 3.
// af from LDS act (contiguous per-wave 1KB reads), 2-buffer, distance 1.
// Swapped mfma(bf, af): lane holds act-row (m*16+lane&15), out-cols wn+n*16+(lane>>4)*4+j.
template<int KT, bool FINAL>
__device__ __forceinline__ void do_layer(
    const f16* __restrict__ Wk, const float* __restrict__ bias,
    f16* __restrict__ act, int rlo, int rhi,
    const int* __restrict__ perm, int slot0, float* __restrict__ out, int t) {
  const int lane = t & 63, wid = t >> 6;
  const int lr = lane & 15, lg = lane >> 4;
  char* actb = (char*)act;

  __syncthreads();                       // previous layer's act writes visible

  if constexpr (!FINAL) {
    const int wn = wid * 64;
    const f16* wp[4];
    #pragma unroll
    for (int n = 0; n < 4; n++)
      wp[n] = Wk + ((wn + n * 16 + lr) * 32 + lg * 8);   // + kt*16384
    const char* ab[2];
    #pragma unroll
    for (int m = 0; m < 2; m++)
      ab[m] = actb + m * 1024 + lg * 256 + lr * 16;      // + kt*2048

    f32x4 acc[2][4];
    #pragma unroll
    for (int m = 0; m < 2; m++)
      #pragma unroll
      for (int n = 0; n < 4; n++) acc[m][n] = f32x4{0.f, 0.f, 0.f, 0.f};

    f16x8 bf[4][4], af[2][2];
    // prologue: bf for kt=0..2 (distance-3 pipe), af for kt=0
    #pragma unroll
    for (int n = 0; n < 4; n++) bf[0][n] = *(const f16x8*)(wp[n]);
    if constexpr (KT > 1) {
      #pragma unroll
      for (int n = 0; n < 4; n++) bf[1][n] = *(const f16x8*)(wp[n] + 16384);
    }
    if constexpr (KT > 2) {
      #pragma unroll
      for (int n = 0; n < 4; n++) bf[2][n] = *(const f16x8*)(wp[n] + 2 * 16384);
    }
    #pragma unroll
    for (int m = 0; m < 2; m++) af[0][m] = *(const f16x8*)(ab[m]);

    #pragma unroll
    for (int kt = 0; kt < KT; kt++) {
      if (kt + 3 < KT) {                 // bf prefetch, distance 3
        #pragma unroll
        for (int n = 0; n < 4; n++)
          bf[(kt + 3) & 3][n] = *(const f16x8*)(wp[n] + (kt + 3) * 16384);
      }
      if (kt + 1 < KT) {                 // af prefetch, distance 1
        #pragma unroll
        for (int m = 0; m < 2; m++)
          af[(kt + 1) & 1][m] = *(const f16x8*)(ab[m] + (kt + 1) * 2048);
      }
      #pragma unroll
      for (int m = 0; m < 2; m++)
        #pragma unroll
        for (int n = 0; n < 4; n++)
          acc[m][n] = MFMA_(bf[kt & 3][n], af[kt & 1][m], acc[m][n]);
    }

    __syncthreads();                     // all af reads done before overwrite

    // epilogue: row r = m*16+lr, out-col c = wn + n*16 + lg*4 (+j)
    // act byte: ((wid*2+(n>>1))*2+m)*1024 + ((n*2+(lg>>1))&3)*256 + lr*16 + (lg&1)*8
    #pragma unroll
    for (int m = 0; m < 2; m++) {
      int r = m * 16 + lr;
      bool ok = (r >= rlo) && (r < rhi);
      #pragma unroll
      for (int n = 0; n < 4; n++) {
        f32x4 bb = *(const f32x4*)(bias + wn + n * 16 + lg * 4);
        f16x4 h;
        #pragma unroll
        for (int j = 0; j < 4; j++)
          h[j] = (f16)fmaxf(acc[m][n][j] + bb[j], 0.f);
        int byte = ((wid * 2 + (n >> 1)) * 2 + m) * 1024
                 + ((n * 2 + (lg >> 1)) & 3) * 256 + lr * 16 + (lg & 1) * 8;
        if (ok)
          *(f16x4*)(actb + byte) = h;
      }
    }
  } else {
    // final 512->64: wave wid -> m-frag mf=wid>>2 (rows mf*16+lr), n-frag nf=wid&3
    const int mf = wid >> 2, nf = wid & 3;
    const f16* wp = Wk + ((nf * 16 + lr) * 32 + lg * 8);   // [kt][64][32], f16-stride 2048
    const char* abf = actb + mf * 1024 + lg * 256 + lr * 16;
    f32x4 a = f32x4{0.f, 0.f, 0.f, 0.f};
    f16x8 wbuf[4], abuf[2];
    wbuf[0] = *(const f16x8*)(wp);
    wbuf[1] = *(const f16x8*)(wp + 2048);
    wbuf[2] = *(const f16x8*)(wp + 2 * 2048);
    abuf[0] = *(const f16x8*)(abf);
    #pragma unroll
    for (int kt = 0; kt < 16; kt++) {
      if (kt + 3 < 16) wbuf[(kt + 3) & 3] = *(const f16x8*)(wp + (kt + 3) * 2048);
      if (kt + 1 < 16) abuf[(kt + 1) & 1] = *(const f16x8*)(abf + (kt + 1) * 2048);
      a = MFMA_(wbuf[kt & 3], abuf[kt & 1], a);
    }
    int r = mf * 16 + lr;
    if (r >= rlo && r < rhi) {
      int orig = perm[slot0 + r];
      int cn0 = nf * 16 + lg * 4;
      f32x4 bb = *(const f32x4*)(bias + cn0);
      f32x4 v;
      #pragma unroll
      for (int j = 0; j < 4; j++) v[j] = a[j] + bb[j];
      *(f32x4*)(out + (long)orig * STY_ + cn0) = v;
    }
  }
}

// ---------------- fused network kernel ----------------
__global__ __launch_bounds__(NTHR, 4) void fused_k(
    const float* __restrict__ x,
    const f16* __restrict__ Wt0, const float* __restrict__ b0,
    const f16* __restrict__ Wt1, const float* __restrict__ b1,
    const f16* __restrict__ Wt2, const float* __restrict__ b2,
    const f16* __restrict__ Wt3, const float* __restrict__ b3,
    const f16* __restrict__ U0t, const float* __restrict__ c0,
    const f16* __restrict__ U1t, const float* __restrict__ c1,
    const f16* __restrict__ U2t, const float* __restrict__ c2,
    const f16* __restrict__ U3t, const float* __restrict__ c3,
    const int* __restrict__ offs, const int* __restrict__ perm,
    float* __restrict__ out) {
  __shared__ f16 act[16 * 32 * 32];        // [kt][m][lg][lr][8], 32 KB

  int t = threadIdx.x;
  // XCD-chunked bijective swizzle (nwg=512, 8 XCDs)
  int wg = (blockIdx.x & 7) * (NBLK / 8) + (blockIdx.x >> 3);
  int slot0 = wg * ROWS;

  // gather x rows via perm into act kt=0 (cols 16..31 zero)
  char* actb = (char*)act;
  #pragma unroll
  for (int i = 0; i < 2; i++) {
    int e = i * NTHR + t;                  // 0..1023
    int r = e >> 5, c = e & 31;
    int orig = perm[slot0 + r];
    f16 v = (c < LAT_) ? (f16)x[orig * LAT_ + c] : (f16)0.f;
    int byte = (r >> 4) * 1024 + ((c >> 3) & 3) * 256 + (r & 15) * 16 + (c & 7) * 2;
    *(f16*)(actb + byte) = v;
  }
  // (do_layer's entry __syncthreads orders these before the first af read)

  // domain span of this block's 32 consecutive slots
  int d0 = 0, d1 = 0;
  #pragma unroll
  for (int d = 1; d < ND_; d++) {
    d0 += (slot0 >= offs[d]);
    d1 += (slot0 + ROWS - 1 >= offs[d]);
  }

  // trunk (shared weights, full row range)
  do_layer<1,  false>(Wt0, b0, act, 0, ROWS, perm, slot0, out, t);
  do_layer<16, false>(Wt1, b1, act, 0, ROWS, perm, slot0, out, t);
  do_layer<16, false>(Wt2, b2, act, 0, ROWS, perm, slot0, out, t);
  do_layer<16, false>(Wt3, b3, act, 0, ROWS, perm, slot0, out, t);

  // experts: boundary blocks (d0<d1) run each layer once per domain, row-masked
  #pragma unroll 1
  for (int d = d0; d <= d1; d++) {
    int rlo = (d == d0) ? 0 : (offs[d] - slot0);
    int rhi = (d == d1) ? ROWS : (offs[d + 1] - slot0);
    do_layer<16, false>(U0t + (long)d * 262144, c0 + d * 512,
                        act, rlo, rhi, perm, slot0, out, t);
  }
  #pragma unroll 1
  for (int d = d0; d <= d1; d++) {
    int rlo = (d == d0) ? 0 : (offs[d] - slot0);
    int rhi = (d == d1) ? ROWS : (offs[d + 1] - slot0);
    do_layer<16, false>(U1t + (long)d * 262144, c1 + d * 512,
                        act, rlo, rhi, perm, slot0, out, t);
  }
  #pragma unroll 1
  for (int d = d0; d <= d1; d++) {
    int rlo = (d == d0) ? 0 : (offs[d] - slot0);
    int rhi = (d == d1) ? ROWS : (offs[d + 1] - slot0);
    do_layer<16, false>(U2t + (long)d * 262144, c2 + d * 512,
                        act, rlo, rhi, perm, slot0, out, t);
  }
  #pragma unroll 1
  for (int d = d0; d <= d1; d++) {
    int rlo = (d == d0) ? 0 : (offs[d] - slot0);
    int rhi = (d == d1) ? ROWS : (offs[d + 1] - slot0);
    do_layer<16, true>(U3t + (long)d * 32768, c3 + d * 64,
                       act, rlo, rhi, perm, slot0, out, t);
  }
}

// ---------------- launch ----------------

extern "C" void kernel_launch(void* const* d_in, const int* in_sizes, int n_in,
                              void* d_out, int out_size, void* d_ws, size_t ws_size,
                              hipStream_t stream) {
  const float* x  = (const float*)d_in[0];
  const int*   y  = (const int*)  d_in[1];
  const float* W0 = (const float*)d_in[2];
  const float* b0 = (const float*)d_in[3];
  const float* W1 = (const float*)d_in[4];
  const float* b1 = (const float*)d_in[5];
  const float* W2 = (const float*)d_in[6];
  const float* b2 = (const float*)d_in[7];
  const float* W3 = (const float*)d_in[8];
  const float* b3 = (const float*)d_in[9];
  const float* U0 = (const float*)d_in[10];
  const float* c0 = (const float*)d_in[11];
  const float* U1 = (const float*)d_in[12];
  const float* c1 = (const float*)d_in[13];
  const float* U2 = (const float*)d_in[14];
  const float* c2 = (const float*)d_in[15];
  const float* U3 = (const float*)d_in[16];
  const float* c3 = (const float*)d_in[17];
  float* out = (float*)d_out;

  char* p = (char*)d_ws;
  auto alloc = [&](size_t bytes) -> char* {
    char* r = p; p += (bytes + 255) & ~(size_t)255; return r;
  };
  f16* Wt0 = (f16*)alloc((size_t)512 * 32 * 2);
  f16* Wt1 = (f16*)alloc((size_t)512 * 512 * 2);
  f16* Wt2 = (f16*)alloc((size_t)512 * 512 * 2);
  f16* Wt3 = (f16*)alloc((size_t)512 * 512 * 2);
  f16* U0t = (f16*)alloc((size_t)ND_ * 512 * 512 * 2);
  f16* U1t = (f16*)alloc((size_t)ND_ * 512 * 512 * 2);
  f16* U2t = (f16*)alloc((size_t)ND_ * 512 * 512 * 2);
  f16* U3t = (f16*)alloc((size_t)ND_ * 16 * 64 * 32 * 2);
  int* offsets = (int*)alloc((ND_ + 1) * 4);
  int* perm    = (int*)alloc((size_t)B_TOT * 4);

  prep_k<<<dim3(16, 16, 36), dim3(32, 8), 0, stream>>>(W0, Wt0, W1, Wt1, W2, Wt2, W3, Wt3,
                                                       U0, U0t, U1, U1t, U2, U2t, U3, U3t);
  bucket_k<<<1, NT_BUCKET, 0, stream>>>(y, offsets, perm);
  fused_k<<<NBLK, NTHR, 0, stream>>>(x, Wt0, b0, Wt1, b1, Wt2, b2, Wt3, b3,
                                     U0t, c0, U1t, c1, U2t, c2, U3t, c3,
                                     offsets, perm, out);
}

// Round 17
// 142.716 us; speedup vs baseline: 1.0503x; 1.0503x over previous
//
#include <hip/hip_runtime.h>
#include <hip/hip_cooperative_groups.h>

namespace cg = cooperative_groups;

typedef _Float16 f16;
typedef _Float16 f16x4 __attribute__((ext_vector_type(4)));
typedef _Float16 f16x8 __attribute__((ext_vector_type(8)));
typedef float f32x4 __attribute__((ext_vector_type(4)));

#define B_TOT 16384
#define LAT_  16
#define STY_  64
#define ND_   8

#define ROWS 64            // rows per block, held in LDS through all 8 layers
#define NTHR 1024          // 16 waves (4 per SIMD)
#define NBLK 256           // 1 block/CU (round 16 proved 2/CU doubles L2 bf: -40%)

#define NTILE 7184         // 16 (W0) + 27*256 (W1..3,U0..2) + 8*32 (U3)

// act LDS layout: f16 [16 kt][4 m][4 lg][16 lr][8]  (64 KB, no pad).
// af fragment read (fixed kt,m): lane (lr+16*lg) reads byte
//   (kt*4+m)*1024 + lg*256 + lr*16 == base + lane*16 -> contiguous 1KB/wave, 0 conflicts.
// Element (row r, col k):
//   byte = ((k>>5)*4 + (r>>4))*1024 + ((k>>3)&3)*256 + (r&15)*16 + (k&7)*2

#define MFMA_(b, a, c) __builtin_amdgcn_mfma_f32_16x16x32_f16((b), (a), (c), 0, 0, 0)

// ---------------- fused layer (phase 2; proven round-12 body) ----------------
// 16 waves; wave wid owns out-cols [wid*32, wid*32+32) (NF=2), all 64 rows (MF=4).
// Weights k-tiled [KT][NR][32]; bf global->VGPR, 4-buffer, distance 3.
// af from LDS act (contiguous per-wave 1KB reads), 2-buffer, distance 1.
// Swapped mfma(bf, af): lane holds act-row (m*16+lane&15), out-cols wn+n*16+(lane>>4)*4+j.
template<int KT, bool FINAL>
__device__ __forceinline__ void do_layer(
    const f16* __restrict__ Wk, const float* __restrict__ bias,
    f16* __restrict__ act, int rlo, int rhi,
    const int* __restrict__ perm, int slot0, float* __restrict__ out, int t) {
  const int lane = t & 63, wid = t >> 6;
  const int lr = lane & 15, lg = lane >> 4;
  char* actb = (char*)act;

  __syncthreads();                       // previous layer's act writes visible

  if constexpr (!FINAL) {
    const int wn = wid * 32;
    const f16* wp[2];
    #pragma unroll
    for (int n = 0; n < 2; n++)
      wp[n] = Wk + ((wn + n * 16 + lr) * 32 + lg * 8);   // + kt*16384
    const char* ab[4];
    #pragma unroll
    for (int m = 0; m < 4; m++)
      ab[m] = actb + m * 1024 + lg * 256 + lr * 16;      // + kt*4096

    f32x4 acc[4][2];
    #pragma unroll
    for (int m = 0; m < 4; m++) {
      acc[m][0] = f32x4{0.f, 0.f, 0.f, 0.f};
      acc[m][1] = f32x4{0.f, 0.f, 0.f, 0.f};
    }

    f16x8 bf[4][2], af[2][4];
    #pragma unroll
    for (int n = 0; n < 2; n++) bf[0][n] = *(const f16x8*)(wp[n]);
    if constexpr (KT > 1) {
      #pragma unroll
      for (int n = 0; n < 2; n++) bf[1][n] = *(const f16x8*)(wp[n] + 16384);
    }
    if constexpr (KT > 2) {
      #pragma unroll
      for (int n = 0; n < 2; n++) bf[2][n] = *(const f16x8*)(wp[n] + 2 * 16384);
    }
    #pragma unroll
    for (int m = 0; m < 4; m++) af[0][m] = *(const f16x8*)(ab[m]);

    #pragma unroll
    for (int kt = 0; kt < KT; kt++) {
      if (kt + 3 < KT) {                 // bf prefetch, distance 3
        #pragma unroll
        for (int n = 0; n < 2; n++)
          bf[(kt + 3) & 3][n] = *(const f16x8*)(wp[n] + (kt + 3) * 16384);
      }
      if (kt + 1 < KT) {                 // af prefetch, distance 1
        #pragma unroll
        for (int m = 0; m < 4; m++)
          af[(kt + 1) & 1][m] = *(const f16x8*)(ab[m] + (kt + 1) * 4096);
      }
      #pragma unroll
      for (int m = 0; m < 4; m++)
        #pragma unroll
        for (int n = 0; n < 2; n++)
          acc[m][n] = MFMA_(bf[kt & 3][n], af[kt & 1][m], acc[m][n]);
    }

    __syncthreads();                     // all af reads done before overwrite

    // epilogue: row r = m*16+lr, out-col cn0 = wn + n*16 + lg*4 (+j)
    #pragma unroll
    for (int m = 0; m < 4; m++) {
      int r = m * 16 + lr;
      bool ok = (r >= rlo) && (r < rhi);
      #pragma unroll
      for (int n = 0; n < 2; n++) {
        f32x4 bb = *(const f32x4*)(bias + wn + n * 16 + lg * 4);
        f16x4 h;
        #pragma unroll
        for (int j = 0; j < 4; j++)
          h[j] = (f16)fmaxf(acc[m][n][j] + bb[j], 0.f);
        int byte = (wid * 4 + m) * 1024 + (n * 2 + (lg >> 1)) * 256
                 + lr * 16 + (lg & 1) * 8;
        if (ok)
          *(f16x4*)(actb + byte) = h;
      }
    }
  } else {
    // final 512->64: wave wid -> m-frag mf=wid>>2 (rows mf*16+lr), n-frag nf=wid&3
    const int mf = wid >> 2, nf = wid & 3;
    const f16* wp = Wk + ((nf * 16 + lr) * 32 + lg * 8);   // [kt][64][32], f16-stride 2048
    const char* abf = actb + mf * 1024 + lg * 256 + lr * 16;
    f32x4 a = f32x4{0.f, 0.f, 0.f, 0.f};
    f16x8 wbuf[4], abuf[2];
    wbuf[0] = *(const f16x8*)(wp);
    wbuf[1] = *(const f16x8*)(wp + 2048);
    wbuf[2] = *(const f16x8*)(wp + 2 * 2048);
    abuf[0] = *(const f16x8*)(abf);
    #pragma unroll
    for (int kt = 0; kt < 16; kt++) {
      if (kt + 3 < 16) wbuf[(kt + 3) & 3] = *(const f16x8*)(wp + (kt + 3) * 2048);
      if (kt + 1 < 16) abuf[(kt + 1) & 1] = *(const f16x8*)(abf + (kt + 1) * 4096);
      a = MFMA_(wbuf[kt & 3], abuf[kt & 1], a);
    }
    int r = mf * 16 + lr;
    if (r >= rlo && r < rhi) {
      int orig = perm[slot0 + r];
      int cn0 = nf * 16 + lg * 4;
      f32x4 bb = *(const f32x4*)(bias + cn0);
      f32x4 v;
      #pragma unroll
      for (int j = 0; j < 4; j++) v[j] = a[j] + bb[j];
      *(f32x4*)(out + (long)orig * STY_ + cn0) = v;
    }
  }
}

// ---------------- single cooperative kernel: prep + bucket, grid.sync, fused --
__global__ __launch_bounds__(NTHR, 4) void mega_k(
    const float* __restrict__ x, const int* __restrict__ y,
    const float* W0, const float* b0, const float* W1, const float* b1,
    const float* W2, const float* b2, const float* W3, const float* b3,
    const float* U0, const float* c0, const float* U1, const float* c1,
    const float* U2, const float* c2, const float* U3, const float* c3,
    f16* Wt0, f16* Wt1, f16* Wt2, f16* Wt3,
    f16* U0t, f16* U1t, f16* U2t, f16* U3t,
    int* __restrict__ offsets, int* __restrict__ perm,
    float* __restrict__ out) {
  __shared__ __align__(16) char smem[65536];   // phase1: tiles/hist; phase2: act

  int t = threadIdx.x;
  int bid = blockIdx.x;

  // ================= phase 1: weight transpose (blocks 0..254) ==============
  if (bid < 255) {
    float (*tile)[32][33] = (float (*)[32][33])smem;   // 4 x 32x33 f32 = 16.9 KB
    int sub = t >> 8, tt = t & 255;
    int tx = tt & 31, ty = tt >> 5;                    // 32 x 8 per sub-tile
    for (int it = 0; it < 8; ++it) {
      int g = (it * 255 + bid) * 4 + sub;
      bool active = (g < NTILE);
      int gg = active ? g : 0;
      // decode worklist: z (tensor slice), nx (out-col tile), ky (k tile)
      int z, nx, ky;
      if (gg < 16)        { z = 0; nx = gg; ky = 0; }
      else if (gg < 6928) { int r = gg - 16; z = 1 + (r >> 8); r &= 255; ky = r >> 4; nx = r & 15; }
      else                { int r = gg - 6928; z = 28 + (r >> 5); r &= 31; nx = r >> 4; ky = r & 15; }
      const float* src; f16* dst; int Kin, Nin, Kpad, NR;
      if (z == 0)      { src = W0; dst = Wt0; Kin = 16;  Nin = 512; Kpad = 32;  NR = 512; }
      else if (z == 1) { src = W1; dst = Wt1; Kin = 512; Nin = 512; Kpad = 512; NR = 512; }
      else if (z == 2) { src = W2; dst = Wt2; Kin = 512; Nin = 512; Kpad = 512; NR = 512; }
      else if (z == 3) { src = W3; dst = Wt3; Kin = 512; Nin = 512; Kpad = 512; NR = 512; }
      else if (z < 12) { int d = z - 4;  src = U0 + (long)d * 262144; dst = U0t + (long)d * 262144; Kin = 512; Nin = 512; Kpad = 512; NR = 512; }
      else if (z < 20) { int d = z - 12; src = U1 + (long)d * 262144; dst = U1t + (long)d * 262144; Kin = 512; Nin = 512; Kpad = 512; NR = 512; }
      else if (z < 28) { int d = z - 20; src = U2 + (long)d * 262144; dst = U2t + (long)d * 262144; Kin = 512; Nin = 512; Kpad = 512; NR = 512; }
      else             { int d = z - 28; src = U3 + (long)d * 32768;  dst = U3t + (long)d * 32768;  Kin = 512; Nin = 64;  Kpad = 512; NR = 64; }

      int k0 = ky * 32, n0 = nx * 32;
      #pragma unroll
      for (int i = 0; i < 32; i += 8) {
        int k = k0 + ty + i, n = n0 + tx;
        tile[sub][ty + i][tx] =
            (active && k < Kin && n < Nin) ? src[(long)k * Nin + n] : 0.f;
      }
      __syncthreads();
      #pragma unroll
      for (int i = 0; i < 32; i += 8) {
        int n = n0 + ty + i, k = k0 + tx;
        if (active && n < NR && k < Kpad)
          dst[(long)(((k >> 5) * NR + n) << 5) | (k & 31)] = (f16)tile[sub][tx][ty + i];
      }
      __syncthreads();
    }
  } else {
    // ============== phase 1: bucketing (block 255, atomics-free) ============
    int (*hist)[NTHR] = (int (*)[NTHR])smem;           // 8 x 1024 ints = 32 KB
    __shared__ int totals[ND_];
    __shared__ int bases[ND_];
    #pragma unroll
    for (int d = 0; d < ND_; d++) hist[d][t] = 0;
    int base = t * 16;
    int yv[16];
    #pragma unroll
    for (int i = 0; i < 16; i++) {
      yv[i] = y[base + i];
      hist[yv[i]][t]++;
    }
    __syncthreads();

    int wave = t >> 6, lane = t & 63;
    if (wave < ND_) {
      int d = wave;
      int carry = 0;
      for (int c = 0; c < NTHR; c += 64) {
        int v = hist[d][c + lane];
        int s = v;
        #pragma unroll
        for (int off = 1; off < 64; off <<= 1) {
          int u = __shfl_up(s, off, 64);
          if (lane >= off) s += u;
        }
        hist[d][c + lane] = carry + s - v;   // exclusive prefix
        carry += __shfl(s, 63, 64);
      }
      if (lane == 0) totals[d] = carry;
    }
    __syncthreads();

    if (t == 0) {
      int s = 0;
      #pragma unroll
      for (int d = 0; d < ND_; d++) { bases[d] = s; offsets[d] = s; s += totals[d]; }
      offsets[ND_] = s;
    }
    __syncthreads();

    #pragma unroll
    for (int i = 0; i < 16; i++) {
      int d = yv[i];
      int pos = bases[d] + hist[d][t];
      hist[d][t]++;
      perm[pos] = base + i;
    }
  }

  // ================= grid-wide sync (transposed weights + perm ready) =======
  cg::this_grid().sync();

  // ================= phase 2: fused 8-layer MLP =============================
  f16* act = (f16*)smem;
  char* actb = smem;

  // XCD-chunked bijective swizzle (nwg=256, 8 XCDs)
  int wg = (bid & 7) * (NBLK / 8) + (bid >> 3);
  int slot0 = wg * ROWS;

  // gather x rows via perm into act kt=0 (cols 16..31 zero)
  #pragma unroll
  for (int i = 0; i < 2; i++) {
    int e = i * NTHR + t;                  // 0..2047
    int r = e >> 5, c = e & 31;
    int orig = perm[slot0 + r];
    f16 v = (c < LAT_) ? (f16)x[orig * LAT_ + c] : (f16)0.f;
    int byte = (r >> 4) * 1024 + ((c >> 3) & 3) * 256 + (r & 15) * 16 + (c & 7) * 2;
    *(f16*)(actb + byte) = v;
  }
  // (do_layer's entry __syncthreads orders these before the first af read)

  // domain span of this block's 64 consecutive slots
  int d0 = 0, d1 = 0;
  #pragma unroll
  for (int d = 1; d < ND_; d++) {
    d0 += (slot0 >= offsets[d]);
    d1 += (slot0 + ROWS - 1 >= offsets[d]);
  }

  // trunk (shared weights, full row range)
  do_layer<1,  false>(Wt0, b0, act, 0, ROWS, perm, slot0, out, t);
  do_layer<16, false>(Wt1, b1, act, 0, ROWS, perm, slot0, out, t);
  do_layer<16, false>(Wt2, b2, act, 0, ROWS, perm, slot0, out, t);
  do_layer<16, false>(Wt3, b3, act, 0, ROWS, perm, slot0, out, t);

  // experts: boundary blocks (d0<d1) run each layer once per domain, row-masked
  #pragma unroll 1
  for (int d = d0; d <= d1; d++) {
    int rlo = (d == d0) ? 0 : (offsets[d] - slot0);
    int rhi = (d == d1) ? ROWS : (offsets[d + 1] - slot0);
    do_layer<16, false>(U0t + (long)d * 262144, c0 + d * 512,
                        act, rlo, rhi, perm, slot0, out, t);
  }
  #pragma unroll 1
  for (int d = d0; d <= d1; d++) {
    int rlo = (d == d0) ? 0 : (offsets[d] - slot0);
    int rhi = (d == d1) ? ROWS : (offsets[d + 1] - slot0);
    do_layer<16, false>(U1t + (long)d * 262144, c1 + d * 512,
                        act, rlo, rhi, perm, slot0, out, t);
  }
  #pragma unroll 1
  for (int d = d0; d <= d1; d++) {
    int rlo = (d == d0) ? 0 : (offsets[d] - slot0);
    int rhi = (d == d1) ? ROWS : (offsets[d + 1] - slot0);
    do_layer<16, false>(U2t + (long)d * 262144, c2 + d * 512,
                        act, rlo, rhi, perm, slot0, out, t);
  }
  #pragma unroll 1
  for (int d = d0; d <= d1; d++) {
    int rlo = (d == d0) ? 0 : (offsets[d] - slot0);
    int rhi = (d == d1) ? ROWS : (offsets[d + 1] - slot0);
    do_layer<16, true>(U3t + (long)d * 32768, c3 + d * 64,
                       act, rlo, rhi, perm, slot0, out, t);
  }
}

// ---------------- launch ----------------

extern "C" void kernel_launch(void* const* d_in, const int* in_sizes, int n_in,
                              void* d_out, int out_size, void* d_ws, size_t ws_size,
                              hipStream_t stream) {
  const float* x  = (const float*)d_in[0];
  const int*   y  = (const int*)  d_in[1];
  const float* W0 = (const float*)d_in[2];
  const float* b0 = (const float*)d_in[3];
  const float* W1 = (const float*)d_in[4];
  const float* b1 = (const float*)d_in[5];
  const float* W2 = (const float*)d_in[6];
  const float* b2 = (const float*)d_in[7];
  const float* W3 = (const float*)d_in[8];
  const float* b3 = (const float*)d_in[9];
  const float* U0 = (const float*)d_in[10];
  const float* c0 = (const float*)d_in[11];
  const float* U1 = (const float*)d_in[12];
  const float* c1 = (const float*)d_in[13];
  const float* U2 = (const float*)d_in[14];
  const float* c2 = (const float*)d_in[15];
  const float* U3 = (const float*)d_in[16];
  const float* c3 = (const float*)d_in[17];
  float* out = (float*)d_out;

  char* p = (char*)d_ws;
  auto alloc = [&](size_t bytes) -> char* {
    char* r = p; p += (bytes + 255) & ~(size_t)255; return r;
  };
  f16* Wt0 = (f16*)alloc((size_t)512 * 32 * 2);
  f16* Wt1 = (f16*)alloc((size_t)512 * 512 * 2);
  f16* Wt2 = (f16*)alloc((size_t)512 * 512 * 2);
  f16* Wt3 = (f16*)alloc((size_t)512 * 512 * 2);
  f16* U0t = (f16*)alloc((size_t)ND_ * 512 * 512 * 2);
  f16* U1t = (f16*)alloc((size_t)ND_ * 512 * 512 * 2);
  f16* U2t = (f16*)alloc((size_t)ND_ * 512 * 512 * 2);
  f16* U3t = (f16*)alloc((size_t)ND_ * 16 * 64 * 32 * 2);
  int* offsets = (int*)alloc((ND_ + 1) * 4);
  int* perm    = (int*)alloc((size_t)B_TOT * 4);

  void* args[] = {
    (void*)&x, (void*)&y,
    (void*)&W0, (void*)&b0, (void*)&W1, (void*)&b1,
    (void*)&W2, (void*)&b2, (void*)&W3, (void*)&b3,
    (void*)&U0, (void*)&c0, (void*)&U1, (void*)&c1,
    (void*)&U2, (void*)&c2, (void*)&U3, (void*)&c3,
    (void*)&Wt0, (void*)&Wt1, (void*)&Wt2, (void*)&Wt3,
    (void*)&U0t, (void*)&U1t, (void*)&U2t, (void*)&U3t,
    (void*)&offsets, (void*)&perm, (void*)&out
  };
  hipLaunchCooperativeKernel((const void*)mega_k, dim3(NBLK), dim3(NTHR),
                             args, 0, stream);
}

// Round 19
// 128.506 us; speedup vs baseline: 1.1665x; 1.1106x over previous
//
#include <hip/hip_runtime.h>

typedef _Float16 f16;
typedef _Float16 f16x4 __attribute__((ext_vector_type(4)));
typedef _Float16 f16x8 __attribute__((ext_vector_type(8)));
typedef float f32x4 __attribute__((ext_vector_type(4)));

#define B_TOT 16384
#define LAT_  16
#define STY_  64
#define ND_   8

#define ROWS 64            // rows per block, held in LDS through all 8 layers
#define NTHR 1024          // 16 waves (4 per SIMD)
#define NBLK 256           // 1 block/CU

// act LDS layout: f16 [16 kt][4 m][4 lg][16 lr][8]  (64 KB).
// af fragment read = contiguous 1KB/wave (lane-linear) -> zero conflicts.
// weight LDS dbuf: f16 [2][16384] (64 KB). Weight GLOBAL layout (lane-linear):
//   f16 idx(n,k) = (k>>5)*(NR*32) + (n>>4)*512 + ((k>>3)&3)*128 + (n&15)*8 + (k&7)
// so a 32-KB k-tile is a linear image where the bf fragment read
// (lane l reads idx = blk*512 + l*8) is exactly the MFMA A-operand layout
// (lane l holds W[n = blk*16 + (l&15)][k = (l>>4)*8 + e]) -> contiguous
// 1KB/wave, zero conflicts, and global_load_lds staging (linear, lane*16B)
// mirrors it exactly (rule #21).

__device__ __forceinline__ void gload16(const f16* g, f16* l) {
  __builtin_amdgcn_global_load_lds(
      (const __attribute__((address_space(1))) unsigned int*)g,
      (__attribute__((address_space(3))) unsigned int*)l, 16, 0, 0);
}

// ---------------- prep: transpose+cast all weights into lane-linear k-tiles --
__global__ void prep_k(const float* W0, f16* Wt0, const float* W1, f16* Wt1,
                       const float* W2, f16* Wt2, const float* W3, f16* Wt3,
                       const float* U0, f16* U0t, const float* U1, f16* U1t,
                       const float* U2, f16* U2t, const float* U3, f16* U3t) {
  int z = blockIdx.z;
  const float* src; f16* dst; int Kin, Nin, Kpad, NR;
  if (z == 0)      { src = W0; dst = Wt0; Kin = 16;  Nin = 512; Kpad = 32;  NR = 512; }
  else if (z == 1) { src = W1; dst = Wt1; Kin = 512; Nin = 512; Kpad = 512; NR = 512; }
  else if (z == 2) { src = W2; dst = Wt2; Kin = 512; Nin = 512; Kpad = 512; NR = 512; }
  else if (z == 3) { src = W3; dst = Wt3; Kin = 512; Nin = 512; Kpad = 512; NR = 512; }
  else if (z < 12) { int d = z - 4;  src = U0 + (long)d * 262144; dst = U0t + (long)d * 262144; Kin = 512; Nin = 512; Kpad = 512; NR = 512; }
  else if (z < 20) { int d = z - 12; src = U1 + (long)d * 262144; dst = U1t + (long)d * 262144; Kin = 512; Nin = 512; Kpad = 512; NR = 512; }
  else if (z < 28) { int d = z - 20; src = U2 + (long)d * 262144; dst = U2t + (long)d * 262144; Kin = 512; Nin = 512; Kpad = 512; NR = 512; }
  else             { int d = z - 28; src = U3 + (long)d * 32768;  dst = U3t + (long)d * 32768;  Kin = 512; Nin = 64;  Kpad = 512; NR = 64; }

  __shared__ float tile[32][33];
  int k0 = blockIdx.y * 32, n0 = blockIdx.x * 32;
  int tx = threadIdx.x, ty = threadIdx.y;  // 32 x 8
  #pragma unroll
  for (int i = 0; i < 32; i += 8) {
    int k = k0 + ty + i, n = n0 + tx;
    tile[ty + i][tx] = (k < Kin && n < Nin) ? src[(long)k * Nin + n] : 0.f;
  }
  __syncthreads();
  #pragma unroll
  for (int i = 0; i < 32; i += 8) {
    int n = n0 + ty + i, k = k0 + tx;
    if (n < NR && k < Kpad) {
      long idx = (long)(k >> 5) * (NR * 32) + (n >> 4) * 512
               + ((k >> 3) & 3) * 128 + (n & 15) * 8 + (k & 7);
      dst[idx] = (f16)tile[tx][ty + i];
    }
  }
}

// ---------------- bucketing (atomics-free, deterministic) ----------------
#define NT_BUCKET 1024
#define RPT 16

__global__ __launch_bounds__(NT_BUCKET) void bucket_k(const int* __restrict__ y,
                                                      int* __restrict__ offsets,
                                                      int* __restrict__ perm) {
  __shared__ int hist[ND_][NT_BUCKET];
  __shared__ int totals[ND_];
  __shared__ int bases[ND_ + 1];
  int t = threadIdx.x;
  int base = t * RPT;

  #pragma unroll
  for (int d = 0; d < ND_; d++) hist[d][t] = 0;
  int yv[RPT];
  #pragma unroll
  for (int i = 0; i < RPT; i++) {
    yv[i] = y[base + i];
    hist[yv[i]][t]++;
  }
  __syncthreads();

  int wave = t >> 6, lane = t & 63;
  if (wave < ND_) {
    int d = wave;
    int carry = 0;
    for (int c = 0; c < NT_BUCKET; c += 64) {
      int v = hist[d][c + lane];
      int s = v;
      #pragma unroll
      for (int off = 1; off < 64; off <<= 1) {
        int u = __shfl_up(s, off, 64);
        if (lane >= off) s += u;
      }
      hist[d][c + lane] = carry + s - v;   // exclusive prefix
      carry += __shfl(s, 63, 64);
    }
    if (lane == 0) totals[d] = carry;
  }
  __syncthreads();

  if (t == 0) {
    int s = 0;
    #pragma unroll
    for (int d = 0; d < ND_; d++) { bases[d] = s; offsets[d] = s; s += totals[d]; }
    offsets[ND_] = s;
  }
  __syncthreads();

  #pragma unroll
  for (int i = 0; i < RPT; i++) {
    int d = yv[i];
    int pos = bases[d] + hist[d][t];
    hist[d][t]++;
    perm[pos] = base + i;
  }
}

#define MFMA_(b, a, c) __builtin_amdgcn_mfma_f32_16x16x32_f16((b), (a), (c), 0, 0, 0)

// ---------------- fused layer ----------------
// 16 waves; wave wid owns out-cols [wid*32, wid*32+32) (NF=2), all 64 rows (MF=4).
// Weights stream global->LDS dbuf via global_load_lds (fire-and-forget DMA):
// per kt: issue STAGE(kt+1) -> ds_read bf/af -> 8 MFMA -> __syncthreads (its
// auto vmcnt(0) drain lands after ~700cy of compute, so L2 latency is hidden
// in the DMA queue, not in wave-stalled VGPR loads = the m97 mechanism).
template<int KT, bool FINAL>
__device__ __forceinline__ void do_layer(
    const f16* __restrict__ Wk, const float* __restrict__ bias,
    f16* __restrict__ act, f16* __restrict__ wls,   // wls = [2][16384] f16
    int rlo, int rhi,
    const int* __restrict__ perm, int slot0, float* __restrict__ out, int t) {
  const int lane = t & 63, wid = t >> 6;
  const int lr = lane & 15, lg = lane >> 4;
  char* actb = (char*)act;

  if constexpr (!FINAL) {
    const int wn = wid * 32;
    const f16* wsrc = Wk + wid * 512 + lane * 8;   // + kt*16384 + i*8192
    const char* ab[4];
    #pragma unroll
    for (int m = 0; m < 4; m++)
      ab[m] = actb + m * 1024 + lg * 256 + lr * 16;      // + kt*4096

    f32x4 acc[4][2];
    #pragma unroll
    for (int m = 0; m < 4; m++) {
      acc[m][0] = f32x4{0.f, 0.f, 0.f, 0.f};
      acc[m][1] = f32x4{0.f, 0.f, 0.f, 0.f};
    }

    // prologue: stage kt=0 into half 0 (touches only wls/global, safe pre-sync);
    // the __syncthreads also orders the previous layer's act writes.
    gload16(wsrc, wls + wid * 512);
    gload16(wsrc + 8192, wls + 8192 + wid * 512);
    __syncthreads();

    #pragma unroll
    for (int kt = 0; kt < KT; kt++) {
      if (kt + 1 < KT) {                 // issue next tile's stage (in flight)
        const f16* s = wsrc + (kt + 1) * 16384;
        f16* d = wls + ((kt + 1) & 1) * 16384;
        gload16(s, d + wid * 512);
        gload16(s + 8192, d + 8192 + wid * 512);
      }
      const f16* wb = wls + (kt & 1) * 16384;
      // lane-linear bf read: lane l gets W[n = blk*16 + (l&15)][(l>>4)*8+e]
      f16x8 b0 = *(const f16x8*)(wb + (wid * 2 + 0) * 512 + lane * 8);
      f16x8 b1 = *(const f16x8*)(wb + (wid * 2 + 1) * 512 + lane * 8);
      f16x8 af[4];
      #pragma unroll
      for (int m = 0; m < 4; m++)
        af[m] = *(const f16x8*)(ab[m] + kt * 4096);
      #pragma unroll
      for (int m = 0; m < 4; m++) {
        acc[m][0] = MFMA_(b0, af[m], acc[m][0]);
        acc[m][1] = MFMA_(b1, af[m], acc[m][1]);
      }
      __syncthreads();                   // drains vmcnt (stage landed) + frees wls[kt&1]
    }

    // epilogue: row r = m*16+lr, out-col cn0 = wn + n*16 + lg*4 (+j)
    #pragma unroll
    for (int m = 0; m < 4; m++) {
      int r = m * 16 + lr;
      bool ok = (r >= rlo) && (r < rhi);
      #pragma unroll
      for (int n = 0; n < 2; n++) {
        f32x4 bb = *(const f32x4*)(bias + wn + n * 16 + lg * 4);
        f16x4 h;
        #pragma unroll
        for (int j = 0; j < 4; j++)
          h[j] = (f16)fmaxf(acc[m][n][j] + bb[j], 0.f);
        int byte = (wid * 4 + m) * 1024 + (n * 2 + (lg >> 1)) * 256
                 + lr * 16 + (lg & 1) * 8;
        if (ok)
          *(f16x4*)(actb + byte) = h;
      }
    }
  } else {
    __syncthreads();                     // previous layer's act writes visible
    // final 512->64: wave wid -> m-frag mf=wid>>2 (rows mf*16+lr), n-frag nf=wid&3
    // lane-linear layout (NR=64): f16 idx = kt*2048 + nf*512 + lg*128 + lr*8
    const int mf = wid >> 2, nf = wid & 3;
    const f16* wp = Wk + nf * 512 + lg * 128 + lr * 8;
    const char* abf = actb + mf * 1024 + lg * 256 + lr * 16;
    f32x4 a = f32x4{0.f, 0.f, 0.f, 0.f};
    f16x8 wbuf[4], abuf[2];
    wbuf[0] = *(const f16x8*)(wp);
    wbuf[1] = *(const f16x8*)(wp + 2048);
    wbuf[2] = *(const f16x8*)(wp + 2 * 2048);
    abuf[0] = *(const f16x8*)(abf);
    #pragma unroll
    for (int kt = 0; kt < 16; kt++) {
      if (kt + 3 < 16) wbuf[(kt + 3) & 3] = *(const f16x8*)(wp + (kt + 3) * 2048);
      if (kt + 1 < 16) abuf[(kt + 1) & 1] = *(const f16x8*)(abf + (kt + 1) * 4096);
      a = MFMA_(wbuf[kt & 3], abuf[kt & 1], a);
    }
    int r = mf * 16 + lr;
    if (r >= rlo && r < rhi) {
      int orig = perm[slot0 + r];
      int cn0 = nf * 16 + lg * 4;
      f32x4 bb = *(const f32x4*)(bias + cn0);
      f32x4 v;
      #pragma unroll
      for (int j = 0; j < 4; j++) v[j] = a[j] + bb[j];
      *(f32x4*)(out + (long)orig * STY_ + cn0) = v;
    }
  }
}

// ---------------- fused network kernel ----------------
__global__ __launch_bounds__(NTHR, 4) void fused_k(
    const float* __restrict__ x,
    const f16* __restrict__ Wt0, const float* __restrict__ b0,
    const f16* __restrict__ Wt1, const float* __restrict__ b1,
    const f16* __restrict__ Wt2, const float* __restrict__ b2,
    const f16* __restrict__ Wt3, const float* __restrict__ b3,
    const f16* __restrict__ U0t, const float* __restrict__ c0,
    const f16* __restrict__ U1t, const float* __restrict__ c1,
    const f16* __restrict__ U2t, const float* __restrict__ c2,
    const f16* __restrict__ U3t, const float* __restrict__ c3,
    const int* __restrict__ offs, const int* __restrict__ perm,
    float* __restrict__ out) {
  __shared__ f16 act[16 * 64 * 32];        // [kt][m][lg][lr][8], 64 KB
  __shared__ f16 wls[2][16384];            // weight double-buffer, 64 KB

  int t = threadIdx.x;
  // XCD-chunked bijective swizzle (nwg=256, 8 XCDs)
  int wg = (blockIdx.x & 7) * (NBLK / 8) + (blockIdx.x >> 3);
  int slot0 = wg * ROWS;

  // gather x rows via perm into act kt=0 (cols 16..31 zero)
  char* actb = (char*)act;
  #pragma unroll
  for (int i = 0; i < 2; i++) {
    int e = i * NTHR + t;                  // 0..2047
    int r = e >> 5, c = e & 31;
    int orig = perm[slot0 + r];
    f16 v = (c < LAT_) ? (f16)x[orig * LAT_ + c] : (f16)0.f;
    int byte = (r >> 4) * 1024 + ((c >> 3) & 3) * 256 + (r & 15) * 16 + (c & 7) * 2;
    *(f16*)(actb + byte) = v;
  }
  // (first do_layer's prologue __syncthreads orders these before af reads)

  // domain span of this block's 64 consecutive slots
  int d0 = 0, d1 = 0;
  #pragma unroll
  for (int d = 1; d < ND_; d++) {
    d0 += (slot0 >= offs[d]);
    d1 += (slot0 + ROWS - 1 >= offs[d]);
  }

  // trunk (shared weights, full row range)
  do_layer<1,  false>(Wt0, b0, act, &wls[0][0], 0, ROWS, perm, slot0, out, t);
  do_layer<16, false>(Wt1, b1, act, &wls[0][0], 0, ROWS, perm, slot0, out, t);
  do_layer<16, false>(Wt2, b2, act, &wls[0][0], 0, ROWS, perm, slot0, out, t);
  do_layer<16, false>(Wt3, b3, act, &wls[0][0], 0, ROWS, perm, slot0, out, t);

  // experts: boundary blocks (d0<d1) run each layer once per domain, row-masked
  #pragma unroll 1
  for (int d = d0; d <= d1; d++) {
    int rlo = (d == d0) ? 0 : (offs[d] - slot0);
    int rhi = (d == d1) ? ROWS : (offs[d + 1] - slot0);
    do_layer<16, false>(U0t + (long)d * 262144, c0 + d * 512,
                        act, &wls[0][0], rlo, rhi, perm, slot0, out, t);
  }
  #pragma unroll 1
  for (int d = d0; d <= d1; d++) {
    int rlo = (d == d0) ? 0 : (offs[d] - slot0);
    int rhi = (d == d1) ? ROWS : (offs[d + 1] - slot0);
    do_layer<16, false>(U1t + (long)d * 262144, c1 + d * 512,
                        act, &wls[0][0], rlo, rhi, perm, slot0, out, t);
  }
  #pragma unroll 1
  for (int d = d0; d <= d1; d++) {
    int rlo = (d == d0) ? 0 : (offs[d] - slot0);
    int rhi = (d == d1) ? ROWS : (offs[d + 1] - slot0);
    do_layer<16, false>(U2t + (long)d * 262144, c2 + d * 512,
                        act, &wls[0][0], rlo, rhi, perm, slot0, out, t);
  }
  #pragma unroll 1
  for (int d = d0; d <= d1; d++) {
    int rlo = (d == d0) ? 0 : (offs[d] - slot0);
    int rhi = (d == d1) ? ROWS : (offs[d + 1] - slot0);
    do_layer<16, true>(U3t + (long)d * 32768, c3 + d * 64,
                       act, &wls[0][0], rlo, rhi, perm, slot0, out, t);
  }
}

// ---------------- launch ----------------

extern "C" void kernel_launch(void* const* d_in, const int* in_sizes, int n_in,
                              void* d_out, int out_size, void* d_ws, size_t ws_size,
                              hipStream_t stream) {
  const float* x  = (const float*)d_in[0];
  const int*   y  = (const int*)  d_in[1];
  const float* W0 = (const float*)d_in[2];
  const float* b0 = (const float*)d_in[3];
  const float* W1 = (const float*)d_in[4];
  const float* b1 = (const float*)d_in[5];
  const float* W2 = (const float*)d_in[6];
  const float* b2 = (const float*)d_in[7];
  const float* W3 = (const float*)d_in[8];
  const float* b3 = (const float*)d_in[9];
  const float* U0 = (const float*)d_in[10];
  const float* c0 = (const float*)d_in[11];
  const float* U1 = (const float*)d_in[12];
  const float* c1 = (const float*)d_in[13];
  const float* U2 = (const float*)d_in[14];
  const float* c2 = (const float*)d_in[15];
  const float* U3 = (const float*)d_in[16];
  const float* c3 = (const float*)d_in[17];
  float* out = (float*)d_out;

  char* p = (char*)d_ws;
  auto alloc = [&](size_t bytes) -> char* {
    char* r = p; p += (bytes + 255) & ~(size_t)255; return r;
  };
  f16* Wt0 = (f16*)alloc((size_t)512 * 32 * 2);
  f16* Wt1 = (f16*)alloc((size_t)512 * 512 * 2);
  f16* Wt2 = (f16*)alloc((size_t)512 * 512 * 2);
  f16* Wt3 = (f16*)alloc((size_t)512 * 512 * 2);
  f16* U0t = (f16*)alloc((size_t)ND_ * 512 * 512 * 2);
  f16* U1t = (f16*)alloc((size_t)ND_ * 512 * 512 * 2);
  f16* U2t = (f16*)alloc((size_t)ND_ * 512 * 512 * 2);
  f16* U3t = (f16*)alloc((size_t)ND_ * 16 * 64 * 32 * 2);
  int* offsets = (int*)alloc((ND_ + 1) * 4);
  int* perm    = (int*)alloc((size_t)B_TOT * 4);

  prep_k<<<dim3(16, 16, 36), dim3(32, 8), 0, stream>>>(W0, Wt0, W1, Wt1, W2, Wt2, W3, Wt3,
                                                       U0, U0t, U1, U1t, U2, U2t, U3, U3t);
  bucket_k<<<1, NT_BUCKET, 0, stream>>>(y, offsets, perm);
  fused_k<<<NBLK, NTHR, 0, stream>>>(x, Wt0, b0, Wt1, b1, Wt2, b2, Wt3, b3,
                                     U0t, c0, U1t, c1, U2t, c2, U3t, c3,
                                     offsets, perm, out);
}

// Round 20
// 113.690 us; speedup vs baseline: 1.3185x; 1.1303x over previous
//
#include <hip/hip_runtime.h>

typedef _Float16 f16;
typedef _Float16 f16x4 __attribute__((ext_vector_type(4)));
typedef _Float16 f16x8 __attribute__((ext_vector_type(8)));
typedef float f32x4 __attribute__((ext_vector_type(4)));

#define B_TOT 16384
#define LAT_  16
#define STY_  64
#define ND_   8

#define ROWS 64            // rows per block, held in LDS through all 8 layers
#define NTHR 1024          // 16 waves (4 per SIMD)
#define NBLK 256           // 1 block/CU

// act LDS layout: f16 [16 kt][4 m][4 lg][16 lr][8]  (64 KB, no pad).
// af fragment read (fixed kt,m): lane (lr+16*lg) reads byte
//   (kt*4+m)*1024 + lg*256 + lr*16 == base + lane*16 -> contiguous 1KB/wave, 0 conflicts.
// Element (row r, col k):
//   byte = ((k>>5)*4 + (r>>4))*1024 + ((k>>3)&3)*256 + (r&15)*16 + (k&7)*2

// ---------------- prep: transpose+cast all weights into k-tiled fragment layout -
// dst elem (out-col n, k) -> dst[((k>>5)*NR + n)*32 + (k&31)]   (f16)
__global__ void prep_k(const float* W0, f16* Wt0, const float* W1, f16* Wt1,
                       const float* W2, f16* Wt2, const float* W3, f16* Wt3,
                       const float* U0, f16* U0t, const float* U1, f16* U1t,
                       const float* U2, f16* U2t, const float* U3, f16* U3t) {
  int z = blockIdx.z;
  const float* src; f16* dst; int Kin, Nin, Kpad, NR;
  if (z == 0)      { src = W0; dst = Wt0; Kin = 16;  Nin = 512; Kpad = 32;  NR = 512; }
  else if (z == 1) { src = W1; dst = Wt1; Kin = 512; Nin = 512; Kpad = 512; NR = 512; }
  else if (z == 2) { src = W2; dst = Wt2; Kin = 512; Nin = 512; Kpad = 512; NR = 512; }
  else if (z == 3) { src = W3; dst = Wt3; Kin = 512; Nin = 512; Kpad = 512; NR = 512; }
  else if (z < 12) { int d = z - 4;  src = U0 + (long)d * 262144; dst = U0t + (long)d * 262144; Kin = 512; Nin = 512; Kpad = 512; NR = 512; }
  else if (z < 20) { int d = z - 12; src = U1 + (long)d * 262144; dst = U1t + (long)d * 262144; Kin = 512; Nin = 512; Kpad = 512; NR = 512; }
  else if (z < 28) { int d = z - 20; src = U2 + (long)d * 262144; dst = U2t + (long)d * 262144; Kin = 512; Nin = 512; Kpad = 512; NR = 512; }
  else             { int d = z - 28; src = U3 + (long)d * 32768;  dst = U3t + (long)d * 32768;  Kin = 512; Nin = 64;  Kpad = 512; NR = 64; }

  __shared__ float tile[32][33];
  int k0 = blockIdx.y * 32, n0 = blockIdx.x * 32;
  int tx = threadIdx.x, ty = threadIdx.y;  // 32 x 8
  #pragma unroll
  for (int i = 0; i < 32; i += 8) {
    int k = k0 + ty + i, n = n0 + tx;
    tile[ty + i][tx] = (k < Kin && n < Nin) ? src[(long)k * Nin + n] : 0.f;
  }
  __syncthreads();
  #pragma unroll
  for (int i = 0; i < 32; i += 8) {
    int n = n0 + ty + i, k = k0 + tx;
    if (n < NR && k < Kpad)
      dst[(long)(((k >> 5) * NR + n) << 5) | (k & 31)] = (f16)tile[tx][ty + i];
  }
}

// ---------------- bucketing (atomics-free, deterministic) ----------------
#define NT_BUCKET 1024
#define RPT 16

__global__ __launch_bounds__(NT_BUCKET) void bucket_k(const int* __restrict__ y,
                                                      int* __restrict__ offsets,
                                                      int* __restrict__ perm) {
  __shared__ int hist[ND_][NT_BUCKET];
  __shared__ int totals[ND_];
  __shared__ int bases[ND_ + 1];
  int t = threadIdx.x;
  int base = t * RPT;

  #pragma unroll
  for (int d = 0; d < ND_; d++) hist[d][t] = 0;
  int yv[RPT];
  #pragma unroll
  for (int i = 0; i < RPT; i++) {
    yv[i] = y[base + i];
    hist[yv[i]][t]++;
  }
  __syncthreads();

  int wave = t >> 6, lane = t & 63;
  if (wave < ND_) {
    int d = wave;
    int carry = 0;
    for (int c = 0; c < NT_BUCKET; c += 64) {
      int v = hist[d][c + lane];
      int s = v;
      #pragma unroll
      for (int off = 1; off < 64; off <<= 1) {
        int u = __shfl_up(s, off, 64);
        if (lane >= off) s += u;
      }
      hist[d][c + lane] = carry + s - v;   // exclusive prefix
      carry += __shfl(s, 63, 64);
    }
    if (lane == 0) totals[d] = carry;
  }
  __syncthreads();

  if (t == 0) {
    int s = 0;
    #pragma unroll
    for (int d = 0; d < ND_; d++) { bases[d] = s; offsets[d] = s; s += totals[d]; }
    offsets[ND_] = s;
  }
  __syncthreads();

  #pragma unroll
  for (int i = 0; i < RPT; i++) {
    int d = yv[i];
    int pos = bases[d] + hist[d][t];
    hist[d][t]++;
    perm[pos] = base + i;
  }
}

#define MFMA_(b, a, c) __builtin_amdgcn_mfma_f32_16x16x32_f16((b), (a), (c), 0, 0, 0)

// ---------------- fused layer (best-measured round-12 body) ----------------
// 16 waves; wave wid owns out-cols [wid*32, wid*32+32) (NF=2), all 64 rows (MF=4).
// Weights k-tiled [KT][NR][32]; bf global->VGPR, 4-buffer, distance 3.
// af from LDS act (contiguous per-wave 1KB reads), 2-buffer, distance 1.
// Swapped mfma(bf, af): lane holds act-row (m*16+lane&15), out-cols wn+n*16+(lane>>4)*4+j.
template<int KT, bool FINAL>
__device__ __forceinline__ void do_layer(
    const f16* __restrict__ Wk, const float* __restrict__ bias,
    f16* __restrict__ act, int rlo, int rhi,
    const int* __restrict__ perm, int slot0, float* __restrict__ out, int t) {
  const int lane = t & 63, wid = t >> 6;
  const int lr = lane & 15, lg = lane >> 4;
  char* actb = (char*)act;

  __syncthreads();                       // previous layer's act writes visible

  if constexpr (!FINAL) {
    const int wn = wid * 32;
    const f16* wp[2];
    #pragma unroll
    for (int n = 0; n < 2; n++)
      wp[n] = Wk + ((wn + n * 16 + lr) * 32 + lg * 8);   // + kt*16384
    const char* ab[4];
    #pragma unroll
    for (int m = 0; m < 4; m++)
      ab[m] = actb + m * 1024 + lg * 256 + lr * 16;      // + kt*4096

    f32x4 acc[4][2];
    #pragma unroll
    for (int m = 0; m < 4; m++) {
      acc[m][0] = f32x4{0.f, 0.f, 0.f, 0.f};
      acc[m][1] = f32x4{0.f, 0.f, 0.f, 0.f};
    }

    f16x8 bf[4][2], af[2][4];
    #pragma unroll
    for (int n = 0; n < 2; n++) bf[0][n] = *(const f16x8*)(wp[n]);
    if constexpr (KT > 1) {
      #pragma unroll
      for (int n = 0; n < 2; n++) bf[1][n] = *(const f16x8*)(wp[n] + 16384);
    }
    if constexpr (KT > 2) {
      #pragma unroll
      for (int n = 0; n < 2; n++) bf[2][n] = *(const f16x8*)(wp[n] + 2 * 16384);
    }
    #pragma unroll
    for (int m = 0; m < 4; m++) af[0][m] = *(const f16x8*)(ab[m]);

    #pragma unroll
    for (int kt = 0; kt < KT; kt++) {
      if (kt + 3 < KT) {                 // bf prefetch, distance 3
        #pragma unroll
        for (int n = 0; n < 2; n++)
          bf[(kt + 3) & 3][n] = *(const f16x8*)(wp[n] + (kt + 3) * 16384);
      }
      if (kt + 1 < KT) {                 // af prefetch, distance 1
        #pragma unroll
        for (int m = 0; m < 4; m++)
          af[(kt + 1) & 1][m] = *(const f16x8*)(ab[m] + (kt + 1) * 4096);
      }
      #pragma unroll
      for (int m = 0; m < 4; m++)
        #pragma unroll
        for (int n = 0; n < 2; n++)
          acc[m][n] = MFMA_(bf[kt & 3][n], af[kt & 1][m], acc[m][n]);
    }

    __syncthreads();                     // all af reads done before overwrite

    // epilogue: row r = m*16+lr, out-col cn0 = wn + n*16 + lg*4 (+j)
    #pragma unroll
    for (int m = 0; m < 4; m++) {
      int r = m * 16 + lr;
      bool ok = (r >= rlo) && (r < rhi);
      #pragma unroll
      for (int n = 0; n < 2; n++) {
        f32x4 bb = *(const f32x4*)(bias + wn + n * 16 + lg * 4);
        f16x4 h;
        #pragma unroll
        for (int j = 0; j < 4; j++)
          h[j] = (f16)fmaxf(acc[m][n][j] + bb[j], 0.f);
        int byte = (wid * 4 + m) * 1024 + (n * 2 + (lg >> 1)) * 256
                 + lr * 16 + (lg & 1) * 8;
        if (ok)
          *(f16x4*)(actb + byte) = h;
      }
    }
  } else {
    // final 512->64: wave wid -> m-frag mf=wid>>2 (rows mf*16+lr), n-frag nf=wid&3
    const int mf = wid >> 2, nf = wid & 3;
    const f16* wp = Wk + ((nf * 16 + lr) * 32 + lg * 8);   // [kt][64][32], f16-stride 2048
    const char* abf = actb + mf * 1024 + lg * 256 + lr * 16;
    f32x4 a = f32x4{0.f, 0.f, 0.f, 0.f};
    f16x8 wbuf[4], abuf[2];
    wbuf[0] = *(const f16x8*)(wp);
    wbuf[1] = *(const f16x8*)(wp + 2048);
    wbuf[2] = *(const f16x8*)(wp + 2 * 2048);
    abuf[0] = *(const f16x8*)(abf);
    #pragma unroll
    for (int kt = 0; kt < 16; kt++) {
      if (kt + 3 < 16) wbuf[(kt + 3) & 3] = *(const f16x8*)(wp + (kt + 3) * 2048);
      if (kt + 1 < 16) abuf[(kt + 1) & 1] = *(const f16x8*)(abf + (kt + 1) * 4096);
      a = MFMA_(wbuf[kt & 3], abuf[kt & 1], a);
    }
    int r = mf * 16 + lr;
    if (r >= rlo && r < rhi) {
      int orig = perm[slot0 + r];
      int cn0 = nf * 16 + lg * 4;
      f32x4 bb = *(const f32x4*)(bias + cn0);
      f32x4 v;
      #pragma unroll
      for (int j = 0; j < 4; j++) v[j] = a[j] + bb[j];
      *(f32x4*)(out + (long)orig * STY_ + cn0) = v;
    }
  }
}

// ---------------- fused network kernel ----------------
__global__ __launch_bounds__(NTHR, 4) void fused_k(
    const float* __restrict__ x,
    const f16* __restrict__ Wt0, const float* __restrict__ b0,
    const f16* __restrict__ Wt1, const float* __restrict__ b1,
    const f16* __restrict__ Wt2, const float* __restrict__ b2,
    const f16* __restrict__ Wt3, const float* __restrict__ b3,
    const f16* __restrict__ U0t, const float* __restrict__ c0,
    const f16* __restrict__ U1t, const float* __restrict__ c1,
    const f16* __restrict__ U2t, const float* __restrict__ c2,
    const f16* __restrict__ U3t, const float* __restrict__ c3,
    const int* __restrict__ offs, const int* __restrict__ perm,
    float* __restrict__ out) {
  __shared__ f16 act[16 * 64 * 32];        // [kt][m][lg][lr][8], 64 KB

  int t = threadIdx.x;
  // XCD-chunked bijective swizzle (nwg=256, 8 XCDs)
  int wg = (blockIdx.x & 7) * (NBLK / 8) + (blockIdx.x >> 3);
  int slot0 = wg * ROWS;

  // gather x rows via perm into act kt=0 (cols 16..31 zero)
  char* actb = (char*)act;
  #pragma unroll
  for (int i = 0; i < 2; i++) {
    int e = i * NTHR + t;                  // 0..2047
    int r = e >> 5, c = e & 31;
    int orig = perm[slot0 + r];
    f16 v = (c < LAT_) ? (f16)x[orig * LAT_ + c] : (f16)0.f;
    int byte = (r >> 4) * 1024 + ((c >> 3) & 3) * 256 + (r & 15) * 16 + (c & 7) * 2;
    *(f16*)(actb + byte) = v;
  }
  // (do_layer's entry __syncthreads orders these before the first af read)

  // domain span of this block's 64 consecutive slots
  int d0 = 0, d1 = 0;
  #pragma unroll
  for (int d = 1; d < ND_; d++) {
    d0 += (slot0 >= offs[d]);
    d1 += (slot0 + ROWS - 1 >= offs[d]);
  }

  // trunk (shared weights, full row range)
  do_layer<1,  false>(Wt0, b0, act, 0, ROWS, perm, slot0, out, t);
  do_layer<16, false>(Wt1, b1, act, 0, ROWS, perm, slot0, out, t);
  do_layer<16, false>(Wt2, b2, act, 0, ROWS, perm, slot0, out, t);
  do_layer<16, false>(Wt3, b3, act, 0, ROWS, perm, slot0, out, t);

  // experts: boundary blocks (d0<d1) run each layer once per domain, row-masked
  #pragma unroll 1
  for (int d = d0; d <= d1; d++) {
    int rlo = (d == d0) ? 0 : (offs[d] - slot0);
    int rhi = (d == d1) ? ROWS : (offs[d + 1] - slot0);
    do_layer<16, false>(U0t + (long)d * 262144, c0 + d * 512,
                        act, rlo, rhi, perm, slot0, out, t);
  }
  #pragma unroll 1
  for (int d = d0; d <= d1; d++) {
    int rlo = (d == d0) ? 0 : (offs[d] - slot0);
    int rhi = (d == d1) ? ROWS : (offs[d + 1] - slot0);
    do_layer<16, false>(U1t + (long)d * 262144, c1 + d * 512,
                        act, rlo, rhi, perm, slot0, out, t);
  }
  #pragma unroll 1
  for (int d = d0; d <= d1; d++) {
    int rlo = (d == d0) ? 0 : (offs[d] - slot0);
    int rhi = (d == d1) ? ROWS : (offs[d + 1] - slot0);
    do_layer<16, false>(U2t + (long)d * 262144, c2 + d * 512,
                        act, rlo, rhi, perm, slot0, out, t);
  }
  #pragma unroll 1
  for (int d = d0; d <= d1; d++) {
    int rlo = (d == d0) ? 0 : (offs[d] - slot0);
    int rhi = (d == d1) ? ROWS : (offs[d + 1] - slot0);
    do_layer<16, true>(U3t + (long)d * 32768, c3 + d * 64,
                       act, rlo, rhi, perm, slot0, out, t);
  }
}

// ---------------- launch ----------------

extern "C" void kernel_launch(void* const* d_in, const int* in_sizes, int n_in,
                              void* d_out, int out_size, void* d_ws, size_t ws_size,
                              hipStream_t stream) {
  const float* x  = (const float*)d_in[0];
  const int*   y  = (const int*)  d_in[1];
  const float* W0 = (const float*)d_in[2];
  const float* b0 = (const float*)d_in[3];
  const float* W1 = (const float*)d_in[4];
  const float* b1 = (const float*)d_in[5];
  const float* W2 = (const float*)d_in[6];
  const float* b2 = (const float*)d_in[7];
  const float* W3 = (const float*)d_in[8];
  const float* b3 = (const float*)d_in[9];
  const float* U0 = (const float*)d_in[10];
  const float* c0 = (const float*)d_in[11];
  const float* U1 = (const float*)d_in[12];
  const float* c1 = (const float*)d_in[13];
  const float* U2 = (const float*)d_in[14];
  const float* c2 = (const float*)d_in[15];
  const float* U3 = (const float*)d_in[16];
  const float* c3 = (const float*)d_in[17];
  float* out = (float*)d_out;

  char* p = (char*)d_ws;
  auto alloc = [&](size_t bytes) -> char* {
    char* r = p; p += (bytes + 255) & ~(size_t)255; return r;
  };
  f16* Wt0 = (f16*)alloc((size_t)512 * 32 * 2);
  f16* Wt1 = (f16*)alloc((size_t)512 * 512 * 2);
  f16* Wt2 = (f16*)alloc((size_t)512 * 512 * 2);
  f16* Wt3 = (f16*)alloc((size_t)512 * 512 * 2);
  f16* U0t = (f16*)alloc((size_t)ND_ * 512 * 512 * 2);
  f16* U1t = (f16*)alloc((size_t)ND_ * 512 * 512 * 2);
  f16* U2t = (f16*)alloc((size_t)ND_ * 512 * 512 * 2);
  f16* U3t = (f16*)alloc((size_t)ND_ * 16 * 64 * 32 * 2);
  int* offsets = (int*)alloc((ND_ + 1) * 4);
  int* perm    = (int*)alloc((size_t)B_TOT * 4);

  prep_k<<<dim3(16, 16, 36), dim3(32, 8), 0, stream>>>(W0, Wt0, W1, Wt1, W2, Wt2, W3, Wt3,
                                                       U0, U0t, U1, U1t, U2, U2t, U3, U3t);
  bucket_k<<<1, NT_BUCKET, 0, stream>>>(y, offsets, perm);
  fused_k<<<NBLK, NTHR, 0, stream>>>(x, Wt0, b0, Wt1, b1, Wt2, b2, Wt3, b3,
                                     U0t, c0, U1t, c1, U2t, c2, U3t, c3,
                                     offsets, perm, out);
}